// Round 3
// baseline (117883.862 us; speedup 1.0000x reference)
//
#include <hip/hip_runtime.h>
#include <stdint.h>

// Problem constants
#define NT 1024
#define NB 64
#define ND 128
#define NH 512
#define NPAIR (NH / 2)   // 256 8-byte units per row

typedef float f32x4  __attribute__((ext_vector_type(4)));
typedef short bf16x8 __attribute__((ext_vector_type(8)));
typedef unsigned int uint32x4 __attribute__((ext_vector_type(4)));
typedef unsigned long long u64;

// Exchange tag: != harness poison 0xAAAAAAAA and != any step tag 1..1024.
#define EXCH_TAG 0x7E57A11Eu

// round-to-nearest-even f32 -> bf16
__device__ __forceinline__ unsigned short f2bf(float f) {
  uint32_t u = __float_as_uint(f);
  u += 0x7fffu + ((u >> 16) & 1u);
  return (unsigned short)(u >> 16);
}

__device__ __forceinline__ bf16x8 cvt8(f32x4 a, f32x4 b) {
  bf16x8 r;
  r[0] = (short)f2bf(a[0]); r[1] = (short)f2bf(a[1]);
  r[2] = (short)f2bf(a[2]); r[3] = (short)f2bf(a[3]);
  r[4] = (short)f2bf(b[0]); r[5] = (short)f2bf(b[1]);
  r[6] = (short)f2bf(b[2]); r[7] = (short)f2bf(b[3]);
  return r;
}

// Remote (agent-scope, IF$-coherent) poll: the round-0-proven path.
// Lane's 8 units: two runs of 4 consecutive units, 16 units apart.
__device__ __forceinline__ void load8_remote(const u64* __restrict__ base,
                                             u64* u) {
#pragma unroll
  for (int i = 0; i < 8; ++i)
    u[i] = __hip_atomic_load(base + (i >> 2) * 16 + (i & 3),
                             __ATOMIC_RELAXED, __HIP_MEMORY_SCOPE_AGENT);
}

// XCD-local poll: sc0 only (bypass per-CU L1, hit the XCD-shared L2).
// Valid only when all group members share one XCD (runtime-verified).
// Producer's plain store is write-through into the SAME physical L2, so it
// updates the line this load re-reads. waitcnt embedded so outputs are
// architecturally valid when the asm block returns.
__device__ __forceinline__ void load8_local(const u64* base, u64* u) {
  asm volatile(
      "global_load_dwordx2 %0, %[a], off sc0\n\t"
      "global_load_dwordx2 %1, %[a], off offset:8 sc0\n\t"
      "global_load_dwordx2 %2, %[a], off offset:16 sc0\n\t"
      "global_load_dwordx2 %3, %[a], off offset:24 sc0\n\t"
      "global_load_dwordx2 %4, %[a], off offset:128 sc0\n\t"
      "global_load_dwordx2 %5, %[a], off offset:136 sc0\n\t"
      "global_load_dwordx2 %6, %[a], off offset:144 sc0\n\t"
      "global_load_dwordx2 %7, %[a], off offset:152 sc0\n\t"
      "s_waitcnt vmcnt(0)"
      : "=&v"(u[0]), "=&v"(u[1]), "=&v"(u[2]), "=&v"(u[3]),
        "=&v"(u[4]), "=&v"(u[5]), "=&v"(u[6]), "=&v"(u[7])
      : [a] "v"(base)
      : "memory");
}

// XCD-local publish: plain store (write-through L1 -> XCD-shared L2).
// 8B unit = tag+payload in one instruction -> single-copy atomic.
__device__ __forceinline__ void store_local(u64* p, u64 w) {
  asm volatile("global_store_dwordx2 %0, %1, off" :: "v"(p), "v"(w) : "memory");
}

// Worker body. Identical protocol on both paths; only the llbuf access
// instructions differ.
template <bool LOCAL>
__device__ __forceinline__ void worker(
    int rg, int cg,
    const float* __restrict__ input,   // [T,B,D]
    const float* __restrict__ W_in,    // [H,D]
    const float* __restrict__ b_in,    // [H]
    const float* __restrict__ W_hid,   // [H,H]
    const float* __restrict__ b_hid,   // [H]
    float* __restrict__ out,           // [T,B,H] fp32
    u64* __restrict__ llbuf,           // [2][B][NPAIR]
    uint32x4 (*lds)[16][64])
{
  const int tid  = threadIdx.x;
  const int wv   = tid >> 6;     // wave 0..3
  const int lane = tid & 63;
  const int col  = lane & 15;
  const int quad = lane >> 4;
  const int kq   = quad * 8;

  // 8 valid batch rows per group; A-tile rows 8..15 are duplicates whose
  // results land in C rows 8..15, which are never stored/published.
  const int bA = rg * 8 + (col & 7);        // input row for A-frag
  const int gB = cg * 64 + wv * 16 + col;   // hidden column (B-frag / C col)
  const int bC = rg * 8 + quad * 4;         // C rows (valid for quad<2 only)

  // poll-lane mapping: lane -> (row, k-quad, chunk pair). Each lane polls 8
  // units = 2 chunks x 4 units; wave wv covers global chunks [wv*4, wv*4+4).
  const int prow = lane & 7;
  const int pq   = (lane >> 3) & 3;
  const int C0   = wv * 4 + (lane >> 5) * 2;

  // stationary weights: B-fragments in registers (bf16)
  bf16x8 Bh[16];
#pragma unroll
  for (int kk = 0; kk < 16; ++kk) {
    const float* p = W_hid + (size_t)gB * NH + kk * 32 + kq;
    Bh[kk] = cvt8(*(const f32x4*)p, *(const f32x4*)(p + 4));
  }
  bf16x8 Bi[4];
#pragma unroll
  for (int kk = 0; kk < 4; ++kk) {
    const float* p = W_in + (size_t)gB * ND + kk * 32 + kq;
    Bi[kk] = cvt8(*(const f32x4*)p, *(const f32x4*)(p + 4));
  }
  const float blane = b_hid[gB] + b_in[gB];

  float v0 = 0.f, v1 = 0.f, v2 = 0.f, v3 = 0.f;
  u64 ua[8];

#pragma unroll 1
  for (int t = 0; t < NT; ++t) {
    const float* ip = input + ((size_t)t * NB + bA) * ND + kq;
    f32x4 x0 = *(const f32x4*)(ip);
    f32x4 x1 = *(const f32x4*)(ip + 4);
    f32x4 x2 = *(const f32x4*)(ip + 32);
    f32x4 x3 = *(const f32x4*)(ip + 36);
    f32x4 x4 = *(const f32x4*)(ip + 64);
    f32x4 x5 = *(const f32x4*)(ip + 68);
    f32x4 x6 = *(const f32x4*)(ip + 96);
    f32x4 x7 = *(const f32x4*)(ip + 100);

    const u64* cbase = llbuf +
        (size_t)((t & 1) * NB + rg * 8 + prow) * NPAIR + C0 * 16 + pq * 4;

    // remote path: issue poll early so IF$ latency overlaps input MFMAs.
    if constexpr (!LOCAL) {
      if (t > 0) load8_remote(cbase, ua);
    }

    // 4 independent accumulators -> dependent-chain depth 5 instead of 20.
    f32x4 a0 = {0.f, 0.f, 0.f, 0.f}, a1 = a0, a2 = a0, a3 = a0;
    a0 = __builtin_amdgcn_mfma_f32_16x16x32_bf16(cvt8(x0, x1), Bi[0], a0, 0, 0, 0);
    a1 = __builtin_amdgcn_mfma_f32_16x16x32_bf16(cvt8(x2, x3), Bi[1], a1, 0, 0, 0);
    a2 = __builtin_amdgcn_mfma_f32_16x16x32_bf16(cvt8(x4, x5), Bi[2], a2, 0, 0, 0);
    a3 = __builtin_amdgcn_mfma_f32_16x16x32_bf16(cvt8(x6, x7), Bi[3], a3, 0, 0, 0);

    if (t > 0) {
      if constexpr (LOCAL) load8_local(cbase, ua);
      int spin = 0;
      for (;;) {
        uint32_t m = 0;
#pragma unroll
        for (int i = 0; i < 8; ++i)
          m |= (uint32_t)(ua[i] >> 32) ^ (uint32_t)t;
        if (m == 0) break;
        if constexpr (LOCAL) {
          if (++spin < 256) {
            load8_local(cbase, ua);     // ~L2 round trip per retry
          } else {
            // escape hatch: same-XCD L2 services its own dirty lines, so
            // agent-scope loads see local-mode stores too.
            __builtin_amdgcn_s_sleep(1);
            load8_remote(cbase, ua);
          }
        } else {
          __builtin_amdgcn_s_sleep(1);
          load8_remote(cbase, ua);
        }
      }
      // deposit: stager (prow,pq,chunk) holds exactly the A-frag units the
      // reader lane (quad=pq, col=prow) needs for chunks C0, C0+1.
      uint32x4 d0 = {(uint32_t)ua[0], (uint32_t)ua[1],
                     (uint32_t)ua[2], (uint32_t)ua[3]};
      uint32x4 d1 = {(uint32_t)ua[4], (uint32_t)ua[5],
                     (uint32_t)ua[6], (uint32_t)ua[7]};
      lds[t & 1][C0][pq * 16 + prow] = d0;
      lds[t & 1][C0 + 1][pq * 16 + prow] = d1;
      __syncthreads();
      // recurrent MFMAs: A-frags from LDS (reader lanes with col>=8 read
      // zero-initialized slots -> garbage confined to C rows 8..15).
#pragma unroll
      for (int kk = 0; kk < 16; kk += 4) {
        uint32x4 p0 = lds[t & 1][kk + 0][lane];
        uint32x4 p1 = lds[t & 1][kk + 1][lane];
        uint32x4 p2 = lds[t & 1][kk + 2][lane];
        uint32x4 p3 = lds[t & 1][kk + 3][lane];
        a0 = __builtin_amdgcn_mfma_f32_16x16x32_bf16(
            __builtin_bit_cast(bf16x8, p0), Bh[kk + 0], a0, 0, 0, 0);
        a1 = __builtin_amdgcn_mfma_f32_16x16x32_bf16(
            __builtin_bit_cast(bf16x8, p1), Bh[kk + 1], a1, 0, 0, 0);
        a2 = __builtin_amdgcn_mfma_f32_16x16x32_bf16(
            __builtin_bit_cast(bf16x8, p2), Bh[kk + 2], a2, 0, 0, 0);
        a3 = __builtin_amdgcn_mfma_f32_16x16x32_bf16(
            __builtin_bit_cast(bf16x8, p3), Bh[kk + 3], a3, 0, 0, 0);
      }
    }

    f32x4 acc = (a0 + a1) + (a2 + a3);

    // v = 0.9 v + 0.1 (S + b); fr = relu(v). Quads 2,3 compute garbage
    // rows; they neither store nor publish.
    v0 = 0.9f * v0 + 0.1f * (acc[0] + blane);
    v1 = 0.9f * v1 + 0.1f * (acc[1] + blane);
    v2 = 0.9f * v2 + 0.1f * (acc[2] + blane);
    v3 = 0.9f * v3 + 0.1f * (acc[3] + blane);
    float f0 = fmaxf(v0, 0.f), f1 = fmaxf(v1, 0.f);
    float f2 = fmaxf(v2, 0.f), f3 = fmaxf(v3, 0.f);

    if (quad < 2) {
      // stream output non-temporally: write-once data, keep L2/IF$ clean
      // so llbuf + input lines stay cache-resident.
      float* op = out + ((size_t)t * NB + bC) * NH + gB;
      __builtin_nontemporal_store(f0, op);
      __builtin_nontemporal_store(f1, op + NH);
      __builtin_nontemporal_store(f2, op + 2 * NH);
      __builtin_nontemporal_store(f3, op + 3 * NH);
    }

    // publish fr_{t+1}: pair with neighbor lane (cols gB, gB^1); even lanes
    // of quads 0,1 store one 8B unit per row: [tag | bf16 | bf16<<16].
    float p0 = __shfl_xor(f0, 1, 64);
    float p1 = __shfl_xor(f1, 1, 64);
    float p2 = __shfl_xor(f2, 1, 64);
    float p3 = __shfl_xor(f3, 1, 64);
    if (quad < 2 && !(lane & 1)) {
      const u64 tagw = ((u64)(uint32_t)(t + 1)) << 32;
      u64* pb = llbuf + (size_t)(((t + 1) & 1) * NB + bC) * NPAIR + (gB >> 1);
      u64 w0 = tagw | (u64)((uint32_t)f2bf(f0) | ((uint32_t)f2bf(p0) << 16));
      u64 w1 = tagw | (u64)((uint32_t)f2bf(f1) | ((uint32_t)f2bf(p1) << 16));
      u64 w2 = tagw | (u64)((uint32_t)f2bf(f2) | ((uint32_t)f2bf(p2) << 16));
      u64 w3 = tagw | (u64)((uint32_t)f2bf(f3) | ((uint32_t)f2bf(p3) << 16));
      if constexpr (LOCAL) {
        store_local(pb + 0 * NPAIR, w0);
        store_local(pb + 1 * NPAIR, w1);
        store_local(pb + 2 * NPAIR, w2);
        store_local(pb + 3 * NPAIR, w3);
      } else {
        __hip_atomic_store(pb + 0 * NPAIR, w0, __ATOMIC_RELAXED, __HIP_MEMORY_SCOPE_AGENT);
        __hip_atomic_store(pb + 1 * NPAIR, w1, __ATOMIC_RELAXED, __HIP_MEMORY_SCOPE_AGENT);
        __hip_atomic_store(pb + 2 * NPAIR, w2, __ATOMIC_RELAXED, __HIP_MEMORY_SCOPE_AGENT);
        __hip_atomic_store(pb + 3 * NPAIR, w3, __ATOMIC_RELAXED, __HIP_MEMORY_SCOPE_AGENT);
      }
    }
  }
}

// Persistent RNN kernel. Grid: exactly 64 WGs (no oversubscription, no claim
// table). WG w: rg = w&7 (8 batch rows), cg = w>>3 (64 hidden cols). Row
// group rg = WGs {rg, rg+8, ..., rg+56}: under round-robin wg->XCD placement
// all 8 members land on XCD rg -> one independent group per XCD, polling at
// XCD-L2 latency. Placement is verified at runtime via an XCC_ID exchange
// through tagged llbuf slots; non-uniform groups fall back to the verified
// round-0 agent-scope protocol.
__global__ __launch_bounds__(256, 1) void rnn_persistent(
    const float* __restrict__ input,
    const float* __restrict__ W_in,
    const float* __restrict__ b_in,
    const float* __restrict__ W_hid,
    const float* __restrict__ b_hid,
    float* __restrict__ out,
    u64* __restrict__ llbuf)
{
  __shared__ uint32x4 lds[2][16][64];  // [parity][chunk][lane] = 32 KB
  __shared__ int s_local;

  const int wg = blockIdx.x;   // 0..63
  const int rg = wg & 7;
  const int cg = wg >> 3;

  // zero LDS once: reader lanes with col>=8 read never-deposited slots, and
  // they must see finite values.
  {
    uint32x4 z = {0u, 0u, 0u, 0u};
    uint32x4* l = &lds[0][0][0];
    for (int i = threadIdx.x; i < 2 * 16 * 64; i += 256) l[i] = z;
  }

  if (threadIdx.x == 0) {
    uint32_t xcc;
    asm volatile("s_getreg_b32 %0, hwreg(HW_REG_XCC_ID)" : "=s"(xcc));
    xcc &= 7u;
    // Exchange via parity-0 unit 0 of each member row. These slots' first
    // real overwrite is member-0's tag-2 publish at t=1, which transitively
    // requires every member to have finished this exchange -> race-free.
    u64* ex = llbuf + (size_t)(rg * 8 + cg) * NPAIR;
    __hip_atomic_store(ex, ((u64)EXCH_TAG << 32) | (u64)xcc,
                       __ATOMIC_RELAXED, __HIP_MEMORY_SCOPE_AGENT);
    int uniform = 1;
    for (int m = 0; m < 8; ++m) {
      const u64* pm = llbuf + (size_t)(rg * 8 + m) * NPAIR;
      u64 v;
      for (;;) {
        v = __hip_atomic_load(pm, __ATOMIC_RELAXED, __HIP_MEMORY_SCOPE_AGENT);
        if ((uint32_t)(v >> 32) == EXCH_TAG) break;
        __builtin_amdgcn_s_sleep(1);
      }
      if ((uint32_t)v != xcc) uniform = 0;  // symmetric: all members agree
    }
    s_local = uniform;
  }
  __syncthreads();

  if (s_local)
    worker<true>(rg, cg, input, W_in, b_in, W_hid, b_hid, out, llbuf, lds);
  else
    worker<false>(rg, cg, input, W_in, b_in, W_hid, b_hid, out, llbuf, lds);
}

extern "C" void kernel_launch(void* const* d_in, const int* in_sizes, int n_in,
                              void* d_out, int out_size, void* d_ws, size_t ws_size,
                              hipStream_t stream) {
  const float* input = (const float*)d_in[0];  // [T,B,D]
  const float* W_in  = (const float*)d_in[1];  // [H,D]
  const float* b_in  = (const float*)d_in[2];  // [H]
  const float* W_hid = (const float*)d_in[3];  // [H,H]
  const float* b_hid = (const float*)d_in[4];  // [H]
  float* out = (float*)d_out;

  // workspace: llbuf[2][B][NPAIR] u64 = 256 KB. Harness poison 0xAA.. gives
  // tag 0xAAAAAAAA != EXCH_TAG and != any t in [1,1024] -> consumers block
  // until real data each dispatch.
  u64* llbuf = (u64*)d_ws;

  hipLaunchKernelGGL(rnn_persistent, dim3(64), dim3(256), 0, stream,
                     input, W_in, b_in, W_hid, b_hid, out, llbuf);
}

// Round 4
// 4105.549 us; speedup vs baseline: 28.7133x; 28.7133x over previous
//
#include <hip/hip_runtime.h>
#include <stdint.h>

// Problem constants
#define NT 1024
#define NB 64
#define ND 128
#define NH 512
#define NPAIR (NH / 2)   // 256 8-byte units per row

typedef float f32x4  __attribute__((ext_vector_type(4)));
typedef short bf16x8 __attribute__((ext_vector_type(8)));
typedef unsigned int uint32x4 __attribute__((ext_vector_type(4)));
typedef unsigned long long u64;

// Exchange tag: != harness poison 0xAAAAAAAA and != any step tag 1..1024.
#define EXCH_TAG 0x7E57A11Eu

// round-to-nearest-even f32 -> bf16
__device__ __forceinline__ unsigned short f2bf(float f) {
  uint32_t u = __float_as_uint(f);
  u += 0x7fffu + ((u >> 16) & 1u);
  return (unsigned short)(u >> 16);
}

__device__ __forceinline__ bf16x8 cvt8(f32x4 a, f32x4 b) {
  bf16x8 r;
  r[0] = (short)f2bf(a[0]); r[1] = (short)f2bf(a[1]);
  r[2] = (short)f2bf(a[2]); r[3] = (short)f2bf(a[3]);
  r[4] = (short)f2bf(b[0]); r[5] = (short)f2bf(b[1]);
  r[6] = (short)f2bf(b[2]); r[7] = (short)f2bf(b[3]);
  return r;
}

// Remote (agent-scope, IF$-coherent) poll: the round-0-proven path.
// Lane's 8 units: two runs of 4 consecutive units, 16 units apart.
__device__ __forceinline__ void load8_remote(const u64* __restrict__ base,
                                             u64* u) {
#pragma unroll
  for (int i = 0; i < 8; ++i)
    u[i] = __hip_atomic_load(base + (i >> 2) * 16 + (i & 3),
                             __ATOMIC_RELAXED, __HIP_MEMORY_SCOPE_AGENT);
}

// XCD-local poll: atomic or-with-0, sc0 (return old value). Atomics cannot
// execute in L1 and, without sc1, execute AT the XCD-shared L2 -- the same
// physical cache the producer's atomic swap executes in (same-XCD membership
// is runtime-verified). This is a guaranteed-fresh L2 read regardless of any
// L1 bypass / store-drain subtleties (round-3 post-mortem).
// Issue phase: 8 atomics, no wait -- latency hides under the input MFMAs.
__device__ __forceinline__ void poll8_issue(const u64* base, u64 zero, u64* u) {
  asm volatile(
      "global_atomic_or_x2 %0, %[a], %[z], off sc0\n\t"
      "global_atomic_or_x2 %1, %[a], %[z], off offset:8 sc0\n\t"
      "global_atomic_or_x2 %2, %[a], %[z], off offset:16 sc0\n\t"
      "global_atomic_or_x2 %3, %[a], %[z], off offset:24 sc0\n\t"
      "global_atomic_or_x2 %4, %[a], %[z], off offset:128 sc0\n\t"
      "global_atomic_or_x2 %5, %[a], %[z], off offset:136 sc0\n\t"
      "global_atomic_or_x2 %6, %[a], %[z], off offset:144 sc0\n\t"
      "global_atomic_or_x2 %7, %[a], %[z], off offset:152 sc0"
      : "=&v"(u[0]), "=&v"(u[1]), "=&v"(u[2]), "=&v"(u[3]),
        "=&v"(u[4]), "=&v"(u[5]), "=&v"(u[6]), "=&v"(u[7])
      : [a] "v"(base), [z] "v"(zero)
      : "memory");
}

// Wait phase: drain vmcnt and make u[] data-dependent on the wait so the
// compiler cannot read the outputs before the hardware writes them.
__device__ __forceinline__ void poll8_wait(u64* u) {
  asm volatile("s_waitcnt vmcnt(0)"
               : "+v"(u[0]), "+v"(u[1]), "+v"(u[2]), "+v"(u[3]),
                 "+v"(u[4]), "+v"(u[5]), "+v"(u[6]), "+v"(u[7])
               :
               : "memory");
}

// Combined issue+wait for the retry loop.
__device__ __forceinline__ void poll8(const u64* base, u64 zero, u64* u) {
  poll8_issue(base, zero, u);
  poll8_wait(u);
}

// XCD-local publish: no-return atomic swap. Executes at the XCD-shared L2
// (no sc1) -> instantly visible to the group's atomic polls. 8B unit =
// tag+payload in one op -> single-copy atomic.
__device__ __forceinline__ void store_local(u64* p, u64 w) {
  asm volatile("global_atomic_swap_x2 %0, %1, off" :: "v"(p), "v"(w)
               : "memory");
}

// Worker body. Identical protocol on both paths; only the llbuf access
// instructions differ. Layout/indexing identical to the round-3-verified
// kernel.
template <bool LOCAL>
__device__ __forceinline__ void worker(
    int rg, int cg,
    const float* __restrict__ input,   // [T,B,D]
    const float* __restrict__ W_in,    // [H,D]
    const float* __restrict__ b_in,    // [H]
    const float* __restrict__ W_hid,   // [H,H]
    const float* __restrict__ b_hid,   // [H]
    float* __restrict__ out,           // [T,B,H] fp32
    u64* __restrict__ llbuf,           // [2][B][NPAIR]
    uint32x4 (*lds)[16][64])
{
  const int tid  = threadIdx.x;
  const int wv   = tid >> 6;     // wave 0..3
  const int lane = tid & 63;
  const int col  = lane & 15;
  const int quad = lane >> 4;
  const int kq   = quad * 8;

  // 8 valid batch rows per group; A-tile rows 8..15 are duplicates whose
  // results land in C rows 8..15, which are never stored/published.
  const int bA = rg * 8 + (col & 7);        // input row for A-frag
  const int gB = cg * 64 + wv * 16 + col;   // hidden column (B-frag / C col)
  const int bC = rg * 8 + quad * 4;         // C rows (valid for quad<2 only)

  // poll-lane mapping: lane -> (row, k-quad, chunk pair). Each lane polls 8
  // units = 2 chunks x 4 units; wave wv covers global chunks [wv*4, wv*4+4).
  const int prow = lane & 7;
  const int pq   = (lane >> 3) & 3;
  const int C0   = wv * 4 + (lane >> 5) * 2;

  // stationary weights: B-fragments in registers (bf16)
  bf16x8 Bh[16];
#pragma unroll
  for (int kk = 0; kk < 16; ++kk) {
    const float* p = W_hid + (size_t)gB * NH + kk * 32 + kq;
    Bh[kk] = cvt8(*(const f32x4*)p, *(const f32x4*)(p + 4));
  }
  bf16x8 Bi[4];
#pragma unroll
  for (int kk = 0; kk < 4; ++kk) {
    const float* p = W_in + (size_t)gB * ND + kk * 32 + kq;
    Bi[kk] = cvt8(*(const f32x4*)p, *(const f32x4*)(p + 4));
  }
  const float blane = b_hid[gB] + b_in[gB];

  float v0 = 0.f, v1 = 0.f, v2 = 0.f, v3 = 0.f;
  u64 ua[8];
  const u64 zero64 = 0ull;

#pragma unroll 1
  for (int t = 0; t < NT; ++t) {
    const float* ip = input + ((size_t)t * NB + bA) * ND + kq;
    f32x4 x0 = *(const f32x4*)(ip);
    f32x4 x1 = *(const f32x4*)(ip + 4);
    f32x4 x2 = *(const f32x4*)(ip + 32);
    f32x4 x3 = *(const f32x4*)(ip + 36);
    f32x4 x4 = *(const f32x4*)(ip + 64);
    f32x4 x5 = *(const f32x4*)(ip + 68);
    f32x4 x6 = *(const f32x4*)(ip + 96);
    f32x4 x7 = *(const f32x4*)(ip + 100);

    const u64* cbase = llbuf +
        (size_t)((t & 1) * NB + rg * 8 + prow) * NPAIR + C0 * 16 + pq * 4;

    // issue poll early: latency (IF$/HBM remote, L2 local) overlaps the
    // input MFMAs below.
    if (t > 0) {
      if constexpr (LOCAL) poll8_issue(cbase, zero64, ua);
      else                 load8_remote(cbase, ua);
    }

    // 4 independent accumulators -> dependent-chain depth 5 instead of 20.
    f32x4 a0 = {0.f, 0.f, 0.f, 0.f}, a1 = a0, a2 = a0, a3 = a0;
    a0 = __builtin_amdgcn_mfma_f32_16x16x32_bf16(cvt8(x0, x1), Bi[0], a0, 0, 0, 0);
    a1 = __builtin_amdgcn_mfma_f32_16x16x32_bf16(cvt8(x2, x3), Bi[1], a1, 0, 0, 0);
    a2 = __builtin_amdgcn_mfma_f32_16x16x32_bf16(cvt8(x4, x5), Bi[2], a2, 0, 0, 0);
    a3 = __builtin_amdgcn_mfma_f32_16x16x32_bf16(cvt8(x6, x7), Bi[3], a3, 0, 0, 0);

    if (t > 0) {
      if constexpr (LOCAL) poll8_wait(ua);
      int spin = 0;
      for (;;) {
        uint32_t m = 0;
#pragma unroll
        for (int i = 0; i < 8; ++i)
          m |= (uint32_t)(ua[i] >> 32) ^ (uint32_t)t;
        if (m == 0) break;
        if constexpr (LOCAL) {
          // same-L2 atomics are coherent by construction; just throttle
          // politely once the wait exceeds a few L2 round trips.
          if (++spin > 64) __builtin_amdgcn_s_sleep(1);
          poll8(cbase, zero64, ua);
        } else {
          __builtin_amdgcn_s_sleep(1);
          load8_remote(cbase, ua);
        }
      }
      // deposit: stager (prow,pq,chunk) holds exactly the A-frag units the
      // reader lane (quad=pq, col=prow) needs for chunks C0, C0+1.
      uint32x4 d0 = {(uint32_t)ua[0], (uint32_t)ua[1],
                     (uint32_t)ua[2], (uint32_t)ua[3]};
      uint32x4 d1 = {(uint32_t)ua[4], (uint32_t)ua[5],
                     (uint32_t)ua[6], (uint32_t)ua[7]};
      lds[t & 1][C0][pq * 16 + prow] = d0;
      lds[t & 1][C0 + 1][pq * 16 + prow] = d1;
      __syncthreads();
      // recurrent MFMAs: A-frags from LDS (reader lanes with col>=8 read
      // zero-initialized slots -> garbage confined to C rows 8..15).
#pragma unroll
      for (int kk = 0; kk < 16; kk += 4) {
        uint32x4 p0 = lds[t & 1][kk + 0][lane];
        uint32x4 p1 = lds[t & 1][kk + 1][lane];
        uint32x4 p2 = lds[t & 1][kk + 2][lane];
        uint32x4 p3 = lds[t & 1][kk + 3][lane];
        a0 = __builtin_amdgcn_mfma_f32_16x16x32_bf16(
            __builtin_bit_cast(bf16x8, p0), Bh[kk + 0], a0, 0, 0, 0);
        a1 = __builtin_amdgcn_mfma_f32_16x16x32_bf16(
            __builtin_bit_cast(bf16x8, p1), Bh[kk + 1], a1, 0, 0, 0);
        a2 = __builtin_amdgcn_mfma_f32_16x16x32_bf16(
            __builtin_bit_cast(bf16x8, p2), Bh[kk + 2], a2, 0, 0, 0);
        a3 = __builtin_amdgcn_mfma_f32_16x16x32_bf16(
            __builtin_bit_cast(bf16x8, p3), Bh[kk + 3], a3, 0, 0, 0);
      }
    }

    f32x4 acc = (a0 + a1) + (a2 + a3);

    // v = 0.9 v + 0.1 (S + b); fr = relu(v). Quads 2,3 compute garbage
    // rows; they neither store nor publish.
    v0 = 0.9f * v0 + 0.1f * (acc[0] + blane);
    v1 = 0.9f * v1 + 0.1f * (acc[1] + blane);
    v2 = 0.9f * v2 + 0.1f * (acc[2] + blane);
    v3 = 0.9f * v3 + 0.1f * (acc[3] + blane);
    float f0 = fmaxf(v0, 0.f), f1 = fmaxf(v1, 0.f);
    float f2 = fmaxf(v2, 0.f), f3 = fmaxf(v3, 0.f);

    if (quad < 2) {
      // stream output non-temporally: write-once data, keep L2 clean so
      // llbuf lines stay L2-resident (critical for the local protocol).
      float* op = out + ((size_t)t * NB + bC) * NH + gB;
      __builtin_nontemporal_store(f0, op);
      __builtin_nontemporal_store(f1, op + NH);
      __builtin_nontemporal_store(f2, op + 2 * NH);
      __builtin_nontemporal_store(f3, op + 3 * NH);
    }

    // publish fr_{t+1}: pair with neighbor lane (cols gB, gB^1); even lanes
    // of quads 0,1 store one 8B unit per row: [tag | bf16 | bf16<<16].
    float p0 = __shfl_xor(f0, 1, 64);
    float p1 = __shfl_xor(f1, 1, 64);
    float p2 = __shfl_xor(f2, 1, 64);
    float p3 = __shfl_xor(f3, 1, 64);
    if (quad < 2 && !(lane & 1)) {
      const u64 tagw = ((u64)(uint32_t)(t + 1)) << 32;
      u64* pb = llbuf + (size_t)(((t + 1) & 1) * NB + bC) * NPAIR + (gB >> 1);
      u64 w0 = tagw | (u64)((uint32_t)f2bf(f0) | ((uint32_t)f2bf(p0) << 16));
      u64 w1 = tagw | (u64)((uint32_t)f2bf(f1) | ((uint32_t)f2bf(p1) << 16));
      u64 w2 = tagw | (u64)((uint32_t)f2bf(f2) | ((uint32_t)f2bf(p2) << 16));
      u64 w3 = tagw | (u64)((uint32_t)f2bf(f3) | ((uint32_t)f2bf(p3) << 16));
      if constexpr (LOCAL) {
        store_local(pb + 0 * NPAIR, w0);
        store_local(pb + 1 * NPAIR, w1);
        store_local(pb + 2 * NPAIR, w2);
        store_local(pb + 3 * NPAIR, w3);
      } else {
        __hip_atomic_store(pb + 0 * NPAIR, w0, __ATOMIC_RELAXED, __HIP_MEMORY_SCOPE_AGENT);
        __hip_atomic_store(pb + 1 * NPAIR, w1, __ATOMIC_RELAXED, __HIP_MEMORY_SCOPE_AGENT);
        __hip_atomic_store(pb + 2 * NPAIR, w2, __ATOMIC_RELAXED, __HIP_MEMORY_SCOPE_AGENT);
        __hip_atomic_store(pb + 3 * NPAIR, w3, __ATOMIC_RELAXED, __HIP_MEMORY_SCOPE_AGENT);
      }
    }
  }
}

// Persistent RNN kernel. Grid: exactly 64 WGs. WG w: rg = w&7 (8 batch
// rows), cg = w>>3 (64 hidden cols). Row group rg = WGs {rg, rg+8, ...,
// rg+56}: under round-robin wg->XCD placement all 8 members land on XCD rg.
// Placement is verified at runtime via an XCC_ID exchange through tagged
// llbuf slots; uniform groups use L2-executed atomics for the fr exchange,
// non-uniform groups fall back to the verified agent-scope protocol.
__global__ __launch_bounds__(256, 1) void rnn_persistent(
    const float* __restrict__ input,
    const float* __restrict__ W_in,
    const float* __restrict__ b_in,
    const float* __restrict__ W_hid,
    const float* __restrict__ b_hid,
    float* __restrict__ out,
    u64* __restrict__ llbuf)
{
  __shared__ uint32x4 lds[2][16][64];  // [parity][chunk][lane] = 32 KB
  __shared__ int s_local;

  const int wg = blockIdx.x;   // 0..63
  const int rg = wg & 7;
  const int cg = wg >> 3;

  // zero LDS once: reader lanes with col>=8 read never-deposited slots, and
  // they must see finite values.
  {
    uint32x4 z = {0u, 0u, 0u, 0u};
    uint32x4* l = &lds[0][0][0];
    for (int i = threadIdx.x; i < 2 * 16 * 64; i += 256) l[i] = z;
  }

  if (threadIdx.x == 0) {
    uint32_t xcc;
    asm volatile("s_getreg_b32 %0, hwreg(HW_REG_XCC_ID)" : "=s"(xcc));
    xcc &= 7u;
    // Exchange via parity-0 unit 0 of each member row. These slots' first
    // real overwrite is the tag-2 publish at t=1, which transitively
    // requires every member to have finished this exchange -> race-free.
    u64* ex = llbuf + (size_t)(rg * 8 + cg) * NPAIR;
    __hip_atomic_store(ex, ((u64)EXCH_TAG << 32) | (u64)xcc,
                       __ATOMIC_RELAXED, __HIP_MEMORY_SCOPE_AGENT);
    int uniform = 1;
    for (int m = 0; m < 8; ++m) {
      const u64* pm = llbuf + (size_t)(rg * 8 + m) * NPAIR;
      u64 v;
      for (;;) {
        v = __hip_atomic_load(pm, __ATOMIC_RELAXED, __HIP_MEMORY_SCOPE_AGENT);
        if ((uint32_t)(v >> 32) == EXCH_TAG) break;
        __builtin_amdgcn_s_sleep(1);
      }
      if ((uint32_t)v != xcc) uniform = 0;  // symmetric: all members agree
    }
    s_local = uniform;
  }
  __syncthreads();

  if (s_local)
    worker<true>(rg, cg, input, W_in, b_in, W_hid, b_hid, out, llbuf, lds);
  else
    worker<false>(rg, cg, input, W_in, b_in, W_hid, b_hid, out, llbuf, lds);
}

extern "C" void kernel_launch(void* const* d_in, const int* in_sizes, int n_in,
                              void* d_out, int out_size, void* d_ws, size_t ws_size,
                              hipStream_t stream) {
  const float* input = (const float*)d_in[0];  // [T,B,D]
  const float* W_in  = (const float*)d_in[1];  // [H,D]
  const float* b_in  = (const float*)d_in[2];  // [H]
  const float* W_hid = (const float*)d_in[3];  // [H,H]
  const float* b_hid = (const float*)d_in[4];  // [H]
  float* out = (float*)d_out;

  // workspace: llbuf[2][B][NPAIR] u64 = 256 KB. Harness poison 0xAA.. gives
  // tag 0xAAAAAAAA != EXCH_TAG and != any t in [1,1024] -> consumers block
  // until real data each dispatch.
  u64* llbuf = (u64*)d_ws;

  hipLaunchKernelGGL(rnn_persistent, dim3(64), dim3(256), 0, stream,
                     input, W_in, b_in, W_hid, b_hid, out, llbuf);
}